// Round 1
// baseline (383.270 us; speedup 1.0000x reference)
//
#include <hip/hip_runtime.h>

// RNN LM fused forward on MI355X (gfx950).
// B=1024, T=256, V=256, H=32.
//
// V2: decoupled two-phase structure (was: 1 barrier per time step).
//  - Phase A: lanes 0..31 of wave 0 run the entire T-step recurrence with h
//    in REGISTERS (lane j owns h_j). Cross-lane h broadcast via v_readlane
//    (no LDS round-trip in the serial chain). Embedding rows prefetched 2
//    steps ahead from global (W_xh stays L1/L2-resident; no LDS staging).
//    Each h_t is written to a full history buffer s_h[256][32] (32 KiB).
//    ZERO barriers inside the loop (single-wave producer).
//  - Phase B: one __syncthreads(), then all 256 threads compute logits for
//    all 256 steps with no further sync. Thread tid owns vocab slot v=tid;
//    h rows broadcast-read from LDS (float4, conflict-free), W_hq column in
//    32 VGPRs, coalesced dword stores (256 consecutive floats per block/t).
// Barriers per block: 257 -> 2. LDS: 33.25 KiB -> 4 blocks/CU.

#define B_SZ 1024
#define T_SZ 256
#define V_SZ 256
#define H_SZ 32

__device__ __forceinline__ float lane_bcast(float v, int lane) {
    return __int_as_float(__builtin_amdgcn_readlane(__float_as_int(v), lane));
}

__global__ __launch_bounds__(256, 4) void rnnlm_fused(
    const int*   __restrict__ X,      // [B, T]
    const float* __restrict__ W_xh,   // [V, H]
    const float* __restrict__ W_hh,   // [H, H]
    const float* __restrict__ b_h,    // [H]
    const float* __restrict__ W_hq,   // [H, V]
    const float* __restrict__ b_q,    // [V]
    float*       __restrict__ out)    // [B, T, V]
{
    __shared__ float s_h[T_SZ][H_SZ];  // 32 KiB: full hidden-state history
    __shared__ int   s_tok[T_SZ];      // this batch's token ids

    const int tid = threadIdx.x;
    const int b   = blockIdx.x;

    // ---- one-time staging ----
    s_tok[tid] = X[b * T_SZ + tid];

    // W_hq column for my vocab slot v = tid (coalesced per j), reused phase B
    float whq[H_SZ];
    #pragma unroll
    for (int j = 0; j < H_SZ; ++j)
        whq[j] = W_hq[j * V_SZ + tid];
    const float bq = b_q[tid];

    __syncthreads();  // s_tok visible to the recurrence wave

    // ---- Phase A: recurrence, lanes 0..31 only, no barriers ----
    if (tid < H_SZ) {
        float whh[H_SZ];  // W_hh column j = tid
        #pragma unroll
        for (int i = 0; i < H_SZ; ++i)
            whh[i] = W_hh[i * H_SZ + tid];
        const float bh = b_h[tid];

        float h = 0.0f;  // h_{-1} = 0; lane j holds h_j
        // prefetch embedding rows 2 steps ahead (hides L1/L2 latency)
        float e_cur = W_xh[s_tok[0] * H_SZ + tid];
        float e_nxt = W_xh[s_tok[1] * H_SZ + tid];

        for (int t = 0; t < T_SZ; ++t) {
            float a0 = e_cur + bh, a1 = 0.0f, a2 = 0.0f, a3 = 0.0f;
            e_cur = e_nxt;
            if (t + 2 < T_SZ)
                e_nxt = W_xh[s_tok[t + 2] * H_SZ + tid];

            // a_j = e_j + b_j + sum_i h_i * W_hh[i][j]
            // h_i gathered via readlane broadcast (VALU, no LDS round-trip)
            #pragma unroll
            for (int i = 0; i < H_SZ; i += 4) {
                a0 += lane_bcast(h, i + 0) * whh[i + 0];
                a1 += lane_bcast(h, i + 1) * whh[i + 1];
                a2 += lane_bcast(h, i + 2) * whh[i + 2];
                a3 += lane_bcast(h, i + 3) * whh[i + 3];
            }
            h = tanhf((a0 + a1) + (a2 + a3));
            s_h[t][tid] = h;  // off the critical chain (never read in phase A)
        }
    }
    __syncthreads();  // full h history ready for all waves

    // ---- Phase B: logits, fully parallel, zero barriers ----
    float* outp = out + (size_t)b * (T_SZ * V_SZ) + tid;
    #pragma unroll 4
    for (int t = 0; t < T_SZ; ++t) {
        const float4* hv = (const float4*)(&s_h[t][0]);  // broadcast reads
        float a0 = bq, a1 = 0.0f, a2 = 0.0f, a3 = 0.0f;
        #pragma unroll
        for (int j = 0; j < H_SZ / 4; ++j) {
            const float4 h4 = hv[j];
            a0 += h4.x * whq[4 * j + 0];
            a1 += h4.y * whq[4 * j + 1];
            a2 += h4.z * whq[4 * j + 2];
            a3 += h4.w * whq[4 * j + 3];
        }
        outp[(size_t)t * V_SZ] = (a0 + a1) + (a2 + a3);  // coalesced
    }
}

extern "C" void kernel_launch(void* const* d_in, const int* in_sizes, int n_in,
                              void* d_out, int out_size, void* d_ws, size_t ws_size,
                              hipStream_t stream) {
    const int*   X    = (const int*)d_in[0];
    const float* W_xh = (const float*)d_in[1];
    const float* W_hh = (const float*)d_in[2];
    const float* b_h  = (const float*)d_in[3];
    const float* W_hq = (const float*)d_in[4];
    const float* b_q  = (const float*)d_in[5];
    float* out = (float*)d_out;

    rnnlm_fused<<<dim3(B_SZ), dim3(256), 0, stream>>>(X, W_xh, W_hh, b_h, W_hq, b_q, out);
}